// Round 2
// 1751.535 us; speedup vs baseline: 1.0828x; 1.0828x over previous
//
#include <hip/hip_runtime.h>
#include <hip/hip_cooperative_groups.h>
#include <cmath>

typedef __bf16 bf16x8 __attribute__((ext_vector_type(8)));
typedef float floatx4 __attribute__((ext_vector_type(4)));
typedef unsigned ux4 __attribute__((ext_vector_type(4)));
typedef unsigned short u16;

#define B_ 16
#define T_ 512
#define D_ 512
#define H_ 1024
#define G_ 2048  // 2H
#define BH (B_ * H_)
#define HP 1032  // lds h row pitch in u16 (+8 elems breaks power-of-2 bank stride)

// ---------------- cast fp32 -> bf16 (RNE) ----------------
__global__ void cast_f32_bf16(const float* __restrict__ src, u16* __restrict__ dst, int n) {
  int i = blockIdx.x * blockDim.x + threadIdx.x;
  int stride = gridDim.x * blockDim.x;
  for (; i < n; i += stride) {
    __bf16 b = (__bf16)src[i];
    dst[i] = *reinterpret_cast<u16*>(&b);
  }
}

// ---------------- w = x @ W^T  (bf16 MFMA, fp32 out), layout w[t][b][2H] ----------------
__launch_bounds__(256, 1)
__global__ void gemm_xW(const u16* __restrict__ xb, const u16* __restrict__ Wb,
                        float* __restrict__ w) {
  const int lane = threadIdx.x & 63;
  const int wv = threadIdx.x >> 6;
  const int rt0 = blockIdx.x * 16;
  const int bidx = rt0 >> 9;
  const int t0 = rt0 & 511;
  const int am = lane & 15;
  const int kq = lane >> 4;

  bf16x8 af[16];
  {
    const u16* xrow = xb + (size_t)(rt0 + am) * D_ + kq * 8;
#pragma unroll
    for (int kk = 0; kk < 16; ++kk)
      af[kk] = *reinterpret_cast<const bf16x8*>(xrow + kk * 32);
  }

#pragma unroll 1
  for (int nt = 0; nt < 32; ++nt) {
    const int n0 = wv * 512 + nt * 16;
    floatx4 acc = {0.f, 0.f, 0.f, 0.f};
    const u16* wrow = Wb + (size_t)(n0 + am) * D_ + kq * 8;
#pragma unroll
    for (int kk = 0; kk < 16; ++kk) {
      bf16x8 bfr = *reinterpret_cast<const bf16x8*>(wrow + kk * 32);
      acc = __builtin_amdgcn_mfma_f32_16x16x32_bf16(af[kk], bfr, acc, 0, 0, 0);
    }
#pragma unroll
    for (int i = 0; i < 4; ++i) {
      int m = kq * 4 + i;
      w[(size_t)((t0 + m) * 16 + bidx) * G_ + n0 + am] = acc[i];
    }
  }
}

// ---------------- in-place LayerNorm over rows of 2048 ----------------
__launch_bounds__(256, 1)
__global__ void layernorm_rows(float* __restrict__ w, const float* __restrict__ gamma,
                               const float* __restrict__ beta) {
  float* r = w + (size_t)blockIdx.x * G_;
  float v[8];
  float s = 0.f, ss = 0.f;
#pragma unroll
  for (int i = 0; i < 8; ++i) {
    v[i] = r[threadIdx.x + i * 256];
    s += v[i];
    ss += v[i] * v[i];
  }
#pragma unroll
  for (int d = 1; d < 64; d <<= 1) {
    s += __shfl_xor(s, d, 64);
    ss += __shfl_xor(ss, d, 64);
  }
  __shared__ float ls[4], lss[4];
  const int wv = threadIdx.x >> 6;
  if ((threadIdx.x & 63) == 0) { ls[wv] = s; lss[wv] = ss; }
  __syncthreads();
  float S = ls[0] + ls[1] + ls[2] + ls[3];
  float SS = lss[0] + lss[1] + lss[2] + lss[3];
  float mu = S * (1.f / 2048.f);
  float var = SS * (1.f / 2048.f) - mu * mu;
  float rs = rsqrtf(var + 1e-5f);
#pragma unroll
  for (int i = 0; i < 8; ++i) {
    int g = threadIdx.x + i * 256;
    r[g] = (v[i] - mu) * rs * gamma[g] + beta[g];
  }
}

// ---------------- persistent LiGRU scan: 2-group batch-pipelined tagged dataflow ----
// Batches are independent recurrences. Split B=16 into two groups of 8; alternate
// phases g=0,1 per step. While group g's h(t+1) crosses the MALL (sc0 sc1, the
// validated system-scope path), the CUs compute group g^1's gates -> the fabric
// round trip overlaps compute instead of serializing with it.
// Protocol per word unchanged: (bf16<<16)|(t+1), fire-and-forget store, tagged
// bundle poll with batched retry. Bundle for each phase is ISSUED at the end of
// the previous phase (one phase after its publish -> visibility elapsed); phase
// start only waits vmcnt + checks tags, with the synchronous retry loop as the
// correctness net. Raw s_barrier + lgkmcnt(0) (not __syncthreads) so barriers
// don't drain the in-flight bundle.
__launch_bounds__(512, 1)
__global__ void ligru_scan(const float* __restrict__ w, const u16* __restrict__ Ub,
                           const float* __restrict__ h0, float* __restrict__ out,
                           unsigned* __restrict__ hbuf) {
  const int tid = threadIdx.x;
  const int lane = tid & 63;
  const int wv = tid >> 6;
  const int am = lane & 15;
  const int kq = lane >> 4;
  const int blk = blockIdx.x;
  const int j0 = blk * 32;
  const int jt = wv >> 1;   // tile 0..3
  const int kh = wv & 1;    // K half

  __shared__ u16 lds_h[16 * HP];         // rows 0..7: active group's batches; 8..15 zero
  __shared__ float lds_r[4][2][16][16];  // [tile][K-half][m-row][n-col] partials

  // zero A rows 8..15 once (MFMA m-rows 8..15 produce discarded zeros)
  for (int i = tid; i < 8 * HP; i += 512) lds_h[8 * HP + i] = 0;

  const int grow = (am < 8) ? (j0 + 8 * jt + am) : (H_ + j0 + 8 * jt + (am - 8));

  // U fragments: 16 gate-rows x K=512 half, register resident
  bf16x8 uf[16];
  {
    const u16* urow = Ub + (size_t)grow * H_ + kh * 512 + kq * 8;
#pragma unroll
    for (int kk = 0; kk < 16; ++kk)
      uf[kk] = *reinterpret_cast<const bf16x8*>(urow + kk * 32);
  }

  // per-thread h ownership: batch ub, col jj; group = sb
  const int ub = tid >> 5;
  const int jj = tid & 31;
  const int col = j0 + jj;
  const int scol = 4 * (tid & 255);
  const int sb = tid >> 8;              // == ub>>3 == my group
  float hreg = h0[col];
  float wa = __builtin_nontemporal_load(&w[(size_t)ub * G_ + col]);
  float wz = __builtin_nontemporal_load(&w[(size_t)ub * G_ + H_ + col]);

  // publish h_0 (tag 1) for owned word; fire-and-forget (system scope)
  {
    __bf16 hb = (__bf16)hreg;
    unsigned pk = ((unsigned)*reinterpret_cast<u16*>(&hb) << 16) | 1u;
    unsigned* pp = hbuf + ub * H_ + col;
    asm volatile("global_store_dword %0, %1, off sc0 sc1"
                 :: "v"(pp), "v"(pk) : "memory");
  }

  ux4 chv[4];
#define ISSUE_BUNDLE(base)                                                   \
  do {                                                                       \
    const unsigned* b_ = (base) + 4 * tid;                                   \
    asm volatile("global_load_dwordx4 %0, %4, off sc0 sc1\n\t"               \
                 "global_load_dwordx4 %1, %5, off sc0 sc1\n\t"               \
                 "global_load_dwordx4 %2, %6, off sc0 sc1\n\t"               \
                 "global_load_dwordx4 %3, %7, off sc0 sc1"                   \
                 : "=&v"(chv[0]), "=&v"(chv[1]), "=&v"(chv[2]), "=&v"(chv[3])\
                 : "v"(b_), "v"(b_ + 2048), "v"(b_ + 4096), "v"(b_ + 6144)   \
                 : "memory");                                                \
  } while (0)

  // initial bundle: (g=0, t=0) = parity 0, group 0, tag 1
  ISSUE_BUNDLE(hbuf);

  for (int t = 0; t < T_; ++t) {
    const unsigned tag = (unsigned)(t + 1);
#pragma unroll 1
    for (int g = 0; g < 2; ++g) {
      // ---- wait for in-flight bundle; tag check; sync retry as fallback ----
      asm volatile("s_waitcnt vmcnt(0)"
                   : "+v"(chv[0]), "+v"(chv[1]), "+v"(chv[2]), "+v"(chv[3])
                   :: "memory");
      __builtin_amdgcn_sched_barrier(0);
      unsigned bad = 0;
#pragma unroll
      for (int c = 0; c < 4; ++c)
        bad |= ((chv[c].x ^ tag) | (chv[c].y ^ tag) |
                (chv[c].z ^ tag) | (chv[c].w ^ tag)) & 0xFFFFu;
      if (bad) {
        const unsigned* cb = hbuf + (size_t)(t & 1) * BH + g * 8192 + 4 * tid;
        unsigned rounds = 0;
        do {
          asm volatile(
              "global_load_dwordx4 %0, %4, off sc0 sc1\n\t"
              "global_load_dwordx4 %1, %5, off sc0 sc1\n\t"
              "global_load_dwordx4 %2, %6, off sc0 sc1\n\t"
              "global_load_dwordx4 %3, %7, off sc0 sc1\n\t"
              "s_waitcnt vmcnt(0)"
              : "=&v"(chv[0]), "=&v"(chv[1]), "=&v"(chv[2]), "=&v"(chv[3])
              : "v"(cb), "v"(cb + 2048), "v"(cb + 4096), "v"(cb + 6144)
              : "memory");
          bad = 0;
#pragma unroll
          for (int c = 0; c < 4; ++c)
            bad |= ((chv[c].x ^ tag) | (chv[c].y ^ tag) |
                    (chv[c].z ^ tag) | (chv[c].w ^ tag)) & 0xFFFFu;
        } while (bad && ++rounds < 2048u);
      }

      // ---- unpack 4 chunks -> LDS rows 0..7 (group g's 8 batches) ----
#pragma unroll
      for (int c = 0; c < 4; ++c) {
        int b = 2 * c + sb;
        unsigned lo = (chv[c].x >> 16) | (chv[c].y & 0xFFFF0000u);
        unsigned hi = (chv[c].z >> 16) | (chv[c].w & 0xFFFF0000u);
        uint2 pk; pk.x = lo; pk.y = hi;
        *reinterpret_cast<uint2*>(&lds_h[b * HP + scol]) = pk;
      }
      asm volatile("s_waitcnt lgkmcnt(0)" ::: "memory");
      __builtin_amdgcn_s_barrier();  // (A) staging complete
      __builtin_amdgcn_sched_barrier(0);

      // ---- gates for group g: D[m=local batch][n=tile col], this wave's K half ----
      floatx4 acc0 = {0, 0, 0, 0}, acc1 = {0, 0, 0, 0};
      {
        const u16* hb = &lds_h[am * HP + kh * 512 + kq * 8];
#pragma unroll
        for (int kk = 0; kk < 8; ++kk) {
          bf16x8 x0 = *reinterpret_cast<const bf16x8*>(hb + (kk + 0) * 32);
          bf16x8 x1 = *reinterpret_cast<const bf16x8*>(hb + (kk + 8) * 32);
          acc0 = __builtin_amdgcn_mfma_f32_16x16x32_bf16(x0, uf[kk + 0], acc0, 0, 0, 0);
          acc1 = __builtin_amdgcn_mfma_f32_16x16x32_bf16(x1, uf[kk + 8], acc1, 0, 0, 0);
        }
      }
      floatx4 acc = acc0 + acc1;

      // park partial gates for cross-wave reduce
#pragma unroll
      for (int i = 0; i < 4; ++i)
        lds_r[jt][kh][kq * 4 + i][am] = acc[i];
      asm volatile("s_waitcnt lgkmcnt(0)" ::: "memory");
      __builtin_amdgcn_s_barrier();  // (B) partials complete
      __builtin_amdgcn_sched_barrier(0);

      // ---- update for group g's batches (waves 4g..4g+3), publish tagged word ----
      float wan = wa, wzn = wz;
      if (sb == g) {
        const int tl = jj >> 3, cc = jj & 7;
        const int mr = ub & 7;
        float a = lds_r[tl][0][mr][cc] + lds_r[tl][1][mr][cc] + wa;
        float z = lds_r[tl][0][mr][8 + cc] + lds_r[tl][1][mr][8 + cc] + wz;
        float zs = 1.f / (1.f + __expf(-z));
        float hn = zs * hreg + (1.f - zs) * fmaxf(a, 0.f);
        hreg = hn;
        __bf16 hb16 = (__bf16)hn;
        unsigned pk = ((unsigned)*reinterpret_cast<u16*>(&hb16) << 16) | (tag + 1u);
        unsigned* pp = hbuf + (size_t)((t + 1) & 1) * BH + ub * H_ + col;
        asm volatile("global_store_dword %0, %1, off sc0 sc1"
                     :: "v"(pp), "v"(pk) : "memory");
        // out store + w prefetch for t+1 (nontemporal stream)
        __builtin_nontemporal_store(hn, &out[((size_t)ub * T_ + t) * H_ + col]);
        int tn = (t + 1 < T_) ? (t + 1) : t;
        const float* wt = w + (size_t)(tn * 16 + ub) * G_;
        wan = __builtin_nontemporal_load(&wt[col]);
        wzn = __builtin_nontemporal_load(&wt[H_ + col]);
      }
      wa = wan; wz = wzn;

      // ---- early-issue bundle for NEXT phase (published one phase ago) ----
      {
        int ntx = (g == 1) ? (t + 1) : t;
        const unsigned* nb = hbuf + (size_t)(ntx & 1) * BH + (g ^ 1) * 8192;
        ISSUE_BUNDLE(nb);
      }
    }
  }
#undef ISSUE_BUNDLE
}

// ---------------- host ----------------
extern "C" void kernel_launch(void* const* d_in, const int* in_sizes, int n_in,
                              void* d_out, int out_size, void* d_ws, size_t ws_size,
                              hipStream_t stream) {
  (void)in_sizes; (void)n_in; (void)out_size; (void)ws_size;
  const float* x = (const float*)d_in[0];
  const float* Ww = (const float*)d_in[1];
  const float* Uw = (const float*)d_in[2];
  const float* gamma = (const float*)d_in[3];
  const float* beta = (const float*)d_in[4];
  const float* h0 = (const float*)d_in[5];
  float* out = (float*)d_out;

  char* p = (char*)d_ws;
  u16* xb = (u16*)p;      p += (size_t)8192 * 512 * 2;   // 8 MB
  u16* Wb = (u16*)p;      p += (size_t)2048 * 512 * 2;   // 2 MB
  u16* Ub = (u16*)p;      p += (size_t)2048 * 1024 * 2;  // 4 MB
  float* w = (float*)p;   p += (size_t)8192 * 2048 * 4;  // 64 MB  [T][B][G]
  unsigned* hbuf = (unsigned*)p; p += (size_t)2 * BH * 4; // 128 KB tagged dwords

  hipMemsetAsync(hbuf, 0, (size_t)2 * BH * 4, stream);  // tag 0 != any real tag
  cast_f32_bf16<<<512, 256, 0, stream>>>(x, xb, 8192 * 512);
  cast_f32_bf16<<<256, 256, 0, stream>>>(Ww, Wb, 2048 * 512);
  cast_f32_bf16<<<256, 256, 0, stream>>>(Uw, Ub, 2048 * 1024);
  gemm_xW<<<512, 256, 0, stream>>>(xb, Wb, w);
  layernorm_rows<<<8192, 256, 0, stream>>>(w, gamma, beta);

  const float* wc = w;
  const u16* Ubc = Ub;
  void* args[5] = { (void*)&wc, (void*)&Ubc, (void*)&h0, (void*)&out, (void*)&hbuf };
  hipLaunchCooperativeKernel((void*)ligru_scan, dim3(32), dim3(512), args, 0, stream);
}